// Round 1
// baseline (204.309 us; speedup 1.0000x reference)
//
#include <hip/hip_runtime.h>

#define Bb 8
#define Ss 50
#define Ii 20
#define Cc 64
#define Nn 4096
#define MAXM 1024
#define BJT 16   // j-tile for LDS staging

// ---------------- K1: masked scatter-add of sums/counts ----------------
__global__ void scatter_kernel(const float* __restrict__ input,
                               const int* __restrict__ ids,
                               const int* __restrict__ seqlen,
                               float* __restrict__ sums,
                               float* __restrict__ counts) {
    int w = (blockIdx.x * blockDim.x + threadIdx.x) >> 6;  // one wave per position
    int lane = threadIdx.x & 63;
    if (w >= Bb * Ss * Ii) return;
    int b = w / (Ss * Ii);
    int rem = w - b * (Ss * Ii);
    int s = rem / Ii;
    if (s >= seqlen[b]) return;          // wave-uniform branch
    int id = ids[w];
    atomicAdd(&sums[((size_t)(b * Nn + id)) * Cc + lane], input[(size_t)w * Cc + lane]);
    if (lane == 0) atomicAdd(&counts[b * Nn + id], 1.0f);
}

// ---------------- K2: compact present means ----------------
__global__ void compact_kernel(const float* __restrict__ sums,
                               const float* __restrict__ counts,
                               int* __restrict__ Mcnt,
                               float* __restrict__ meansC) {
    int w = (blockIdx.x * blockDim.x + threadIdx.x) >> 6;  // one wave per (b,n)
    int lane = threadIdx.x & 63;
    int b = w >> 12;
    int n = w & (Nn - 1);
    float cnt = counts[b * Nn + n];
    int j = 0;
    if (lane == 0 && cnt > 0.f) j = atomicAdd(&Mcnt[b], 1);
    j = __shfl(j, 0);
    if (cnt > 0.f) {
        float inv = 1.0f / cnt;
        meansC[((size_t)b * MAXM + j) * Cc + lane] =
            sums[((size_t)(b * Nn + n)) * Cc + lane] * inv;
    }
}

// ---------------- K3: f = E @ W, cvec = E @ bias ----------------
__global__ void proj_kernel(const float* __restrict__ E,
                            const float* __restrict__ W,
                            const float* __restrict__ bias,
                            float* __restrict__ Fbuf,
                            float* __restrict__ cvec) {
    __shared__ float wlds[Cc * Cc];   // 16 KB
    __shared__ float elds[4 * Cc];
    int tid = threadIdx.x;
    int n0 = blockIdx.x * 4;
#pragma unroll
    for (int i = 0; i < 16; i++) wlds[tid + 256 * i] = W[tid + 256 * i];
    int nl = tid >> 6, k = tid & 63;
    elds[tid] = E[(size_t)(n0 + nl) * Cc + k];
    __syncthreads();
    float acc = 0.f;
#pragma unroll
    for (int c = 0; c < Cc; c++) acc = fmaf(elds[nl * Cc + c], wlds[c * Cc + k], acc);
    Fbuf[(size_t)(n0 + nl) * Cc + k] = acc;
    float p = elds[nl * Cc + k] * bias[k];
#pragma unroll
    for (int off = 32; off; off >>= 1) p += __shfl_down(p, off);
    if (k == 0) cvec[n0 + nl] = p;
}

// ---------------- K4: fused scores/softmax/combine/project ----------------
__global__ __launch_bounds__(256, 2) void main_kernel(
    const float* __restrict__ E, const float* __restrict__ Fbuf,
    const float* __restrict__ cvec, const float* __restrict__ meansC,
    const int* __restrict__ Mcnt, float* __restrict__ out) {
    int b = blockIdx.x & 7;           // batch interleave for load balance
    int ntile = blockIdx.x >> 3;
    int tid = threadIdx.x;
    int t = tid >> 6;                 // wave index = j-split lane
    int nl = tid & 63;
    int n = ntile * 64 + nl;

    __shared__ __align__(16) float smean[2][BJT * Cc];  // 2 x 4 KB
    __shared__ float red[3][256];

    float4 e4[16], f4[16];
    const float4* ep = (const float4*)(E + (size_t)n * Cc);
    const float4* fp = (const float4*)(Fbuf + (size_t)n * Cc);
#pragma unroll
    for (int i = 0; i < 16; i++) { e4[i] = ep[i]; f4[i] = fp[i]; }

    int M = Mcnt[b];
    const float* mb = meansC + (size_t)b * MAXM * Cc;
    int ntiles = (M + BJT - 1) / BJT;

    // preload tile 0
    ((float4*)smean[0])[tid] = ((const float4*)mb)[tid];

    float m0 = -1e30f, l = 0.f, accv = 0.f;

    for (int jt = 0; jt < ntiles; jt++) {
        __syncthreads();
        if (jt + 1 < ntiles) {
            const float4* src = (const float4*)(mb + (size_t)(jt + 1) * BJT * Cc);
            ((float4*)smean[(jt + 1) & 1])[tid] = src[tid];
        }
        const float* buf = smean[jt & 1];
        int jbase = jt * BJT;
#pragma unroll
        for (int jj = 0; jj < BJT / 4; jj++) {
            int jl = jj * 4 + t;
            int j = jbase + jl;
            if (j < M) {                       // wave-uniform
                const float4* mv4 = (const float4*)(buf + jl * Cc);
                float de = 0.f, df = 0.f;
#pragma unroll
                for (int c4 = 0; c4 < 16; c4++) {
                    float4 mv = mv4[c4];
                    de = fmaf(mv.x, e4[c4].x, de);
                    de = fmaf(mv.y, e4[c4].y, de);
                    de = fmaf(mv.z, e4[c4].z, de);
                    de = fmaf(mv.w, e4[c4].w, de);
                    df = fmaf(mv.x, f4[c4].x, df);
                    df = fmaf(mv.y, f4[c4].y, df);
                    df = fmaf(mv.z, f4[c4].z, df);
                    df = fmaf(mv.w, f4[c4].w, df);
                }
                float s = de > 0.f ? de : 0.2f * de;   // leaky_relu 0.2
                float ex = __expf(-fabsf(s - m0));
                bool sg = s > m0;
                float p = sg ? 1.0f : ex;
                float alpha = sg ? ex : 1.0f;
                m0 = fmaxf(m0, s);
                l = l * alpha + p;
                accv = accv * alpha + p * df;
            }
        }
    }

    red[0][tid] = m0; red[1][tid] = l; red[2][tid] = accv;
    __syncthreads();
    if (t == 0) {
        float M0 = -1e30f;
#pragma unroll
        for (int q = 0; q < 4; q++) M0 = fmaxf(M0, red[0][nl + 64 * q]);
        float L = 0.f, A = 0.f;
#pragma unroll
        for (int q = 0; q < 4; q++) {
            float w = __expf(red[0][nl + 64 * q] - M0);
            L += red[1][nl + 64 * q] * w;
            A += red[2][nl + 64 * q] * w;
        }
        out[(size_t)b * Nn + n] = A / L + cvec[n];
    }
}

extern "C" void kernel_launch(void* const* d_in, const int* in_sizes, int n_in,
                              void* d_out, int out_size, void* d_ws, size_t ws_size,
                              hipStream_t stream) {
    (void)in_sizes; (void)n_in; (void)out_size; (void)ws_size;
    const float* input  = (const float*)d_in[0];   // (B,S,I,C)
    const float* E      = (const float*)d_in[1];   // (N,C)
    const float* W      = (const float*)d_in[2];   // (C,C)
    const float* bias   = (const float*)d_in[3];   // (C,)
    const int*   ids    = (const int*)d_in[4];     // (B,S,I)
    const int*   seqlen = (const int*)d_in[5];     // (B,)
    float* out = (float*)d_out;

    // workspace layout (floats)
    float* sums   = (float*)d_ws;                       // B*N*C
    float* counts = sums + (size_t)Bb * Nn * Cc;        // B*N
    int*   Mcnt   = (int*)(counts + Bb * Nn);           // 16 ints (8 used, pad)
    float* meansC = (float*)(Mcnt + 16);                // B*MAXM*C
    float* Fbuf   = meansC + (size_t)Bb * MAXM * Cc;    // N*C
    float* cvec   = Fbuf + (size_t)Nn * Cc;             // N

    size_t zero_bytes = ((size_t)Bb * Nn * Cc + Bb * Nn + 16) * sizeof(float);
    hipMemsetAsync(d_ws, 0, zero_bytes, stream);

    // K1: scatter  (B*S*I = 8000 waves, 4 waves/block)
    scatter_kernel<<<(Bb * Ss * Ii + 3) / 4, 256, 0, stream>>>(input, ids, seqlen, sums, counts);
    // K2: compact  (B*N waves, 4/block)
    compact_kernel<<<Bb * Nn / 4, 256, 0, stream>>>(sums, counts, Mcnt, meansC);
    // K3: f = E@W, cvec
    proj_kernel<<<Nn / 4, 256, 0, stream>>>(E, W, bias, Fbuf, cvec);
    // K4: fused main
    main_kernel<<<Bb * (Nn / 64), 256, 0, stream>>>(E, Fbuf, cvec, meansC, Mcnt, out);
}

// Round 2
// 188.345 us; speedup vs baseline: 1.0848x; 1.0848x over previous
//
#include <hip/hip_runtime.h>

#define Bb 8
#define Ss 50
#define Ii 20
#define Cc 64
#define Nn 4096
#define MAXM 1024
#define JSPLIT 4
#define NPOS (Bb * Ss * Ii)   // 8000

// ---------------- K1: presence counts (int) ----------------
__global__ void count_kernel(const int* __restrict__ ids,
                             const int* __restrict__ seqlen,
                             int* __restrict__ cnt) {
    int idx = blockIdx.x * blockDim.x + threadIdx.x;
    if (idx >= NPOS) return;
    int b = idx / (Ss * Ii);
    int rem = idx - b * (Ss * Ii);
    int s = rem / Ii;
    if (s >= seqlen[b]) return;
    atomicAdd(&cnt[b * Nn + ids[idx]], 1);
}

// ---------------- K2: slot assignment + inverse counts ----------------
__global__ void slot_kernel(const int* __restrict__ cnt,
                            int* __restrict__ Mcnt,
                            int* __restrict__ slotmap,
                            float* __restrict__ invc) {
    int idx = blockIdx.x * blockDim.x + threadIdx.x;   // B*N threads
    int b = idx >> 12;
    int c = cnt[idx];
    if (c > 0) {
        int slot = atomicAdd(&Mcnt[b], 1);
        slotmap[idx] = slot;
        invc[idx] = 1.0f / (float)c;
    }
}

// ---------------- K3: scatter pre-scaled values into compact mean slots ----------------
__global__ void scatter_kernel(const float* __restrict__ input,
                               const int* __restrict__ ids,
                               const int* __restrict__ seqlen,
                               const int* __restrict__ slotmap,
                               const float* __restrict__ invc,
                               float* __restrict__ meansC) {
    int w = (blockIdx.x * blockDim.x + threadIdx.x) >> 6;  // one wave per position
    int lane = threadIdx.x & 63;
    if (w >= NPOS) return;
    int b = w / (Ss * Ii);
    int rem = w - b * (Ss * Ii);
    int s = rem / Ii;
    if (s >= seqlen[b]) return;          // wave-uniform
    int id = ids[w];
    int slot = slotmap[b * Nn + id];
    float v = input[(size_t)w * Cc + lane] * invc[b * Nn + id];
    atomicAdd(&meansC[((size_t)b * MAXM + slot) * Cc + lane], v);
}

// ---------------- K4: f = E @ W^T rows folded:  F[n] = E[n] @ W ; cvec = E @ bias ----------------
__global__ void proj_kernel(const float* __restrict__ E,
                            const float* __restrict__ W,
                            const float* __restrict__ bias,
                            float* __restrict__ Fbuf,
                            float* __restrict__ cvec) {
    __shared__ float wlds[Cc * Cc];   // 16 KB
    __shared__ float elds[4 * Cc];
    int tid = threadIdx.x;
    int n0 = blockIdx.x * 4;
#pragma unroll
    for (int i = 0; i < 16; i++) wlds[tid + 256 * i] = W[tid + 256 * i];
    int nl = tid >> 6, k = tid & 63;
    elds[tid] = E[(size_t)(n0 + nl) * Cc + k];
    __syncthreads();
    float acc = 0.f;
#pragma unroll
    for (int c = 0; c < Cc; c++) acc = fmaf(elds[nl * Cc + c], wlds[c * Cc + k], acc);
    Fbuf[(size_t)(n0 + nl) * Cc + k] = acc;
    float p = elds[nl * Cc + k] * bias[k];
#pragma unroll
    for (int off = 32; off; off >>= 1) p += __shfl_down(p, off);
    if (k == 0) cvec[n0 + nl] = p;
}

// ---------------- K5: fused scores/online-softmax/combine (partials per j-split) ----------------
__global__ __launch_bounds__(256, 2) void main_kernel(
    const float* __restrict__ E, const float* __restrict__ Fbuf,
    const float* __restrict__ meansC, const int* __restrict__ Mcnt,
    float* __restrict__ partials) {
    // blockIdx = (b*JSPLIT + s)*64 + ntile  (ntile fastest -> co-resident blocks share mean range)
    int ntile = blockIdx.x & 63;
    int bs = blockIdx.x >> 6;
    int s = bs & (JSPLIT - 1);
    int b = bs >> 2;
    int tid = threadIdx.x;
    int t = tid >> 6;            // wave id: 4-way j-split within block
    int lane = tid & 63;
    int n = ntile * 64 + lane;

    int M = Mcnt[b];
    int chunk = (M + JSPLIT - 1) / JSPLIT;
    int j0 = s * chunk;
    int j1 = min(M, j0 + chunk);

    float* pbase = partials + ((size_t)(b * JSPLIT + s) * 3) * Nn + n;
    if (j0 >= j1) {               // empty split: must still write (ws is poisoned)
        if (t == 0) { pbase[0] = -1e30f; pbase[Nn] = 0.f; pbase[2 * Nn] = 0.f; }
        return;
    }

    // resident E/F rows: 128 VGPRs, pinned via empty-asm (non-rematerializable)
    float4 e4[16], f4[16];
    const float4* ep = (const float4*)(E + (size_t)n * Cc);
    const float4* fp = (const float4*)(Fbuf + (size_t)n * Cc);
#pragma unroll
    for (int i = 0; i < 16; i++) { e4[i] = ep[i]; f4[i] = fp[i]; }
#pragma unroll
    for (int i = 0; i < 16; i++) {
        asm volatile("" : "+v"(e4[i].x), "+v"(e4[i].y), "+v"(e4[i].z), "+v"(e4[i].w));
        asm volatile("" : "+v"(f4[i].x), "+v"(f4[i].y), "+v"(f4[i].z), "+v"(f4[i].w));
    }

    const float* mb = meansC + (size_t)b * MAXM * Cc;
    float m0 = -1e30f, l = 0.f, accv = 0.f;

    for (int j = j0 + t; j < j1; j += 4) {
        int ju = __builtin_amdgcn_readfirstlane(j);          // wave-uniform address
        const float4* mv4 = (const float4*)(mb + (size_t)ju * Cc);
        float de = 0.f, df = 0.f;
#pragma unroll
        for (int c4 = 0; c4 < 16; c4++) {
            float4 mv = mv4[c4];
            de = fmaf(mv.x, e4[c4].x, de);
            de = fmaf(mv.y, e4[c4].y, de);
            de = fmaf(mv.z, e4[c4].z, de);
            de = fmaf(mv.w, e4[c4].w, de);
            df = fmaf(mv.x, f4[c4].x, df);
            df = fmaf(mv.y, f4[c4].y, df);
            df = fmaf(mv.z, f4[c4].z, df);
            df = fmaf(mv.w, f4[c4].w, df);
        }
        float sc = de > 0.f ? de : 0.2f * de;     // leaky_relu 0.2
        float ex = __expf(-fabsf(sc - m0));
        bool sg = sc > m0;
        float p = sg ? 1.0f : ex;
        float alpha = sg ? ex : 1.0f;
        m0 = fmaxf(m0, sc);
        l = l * alpha + p;
        accv = accv * alpha + p * df;
    }

    __shared__ float red[3][256];
    red[0][tid] = m0; red[1][tid] = l; red[2][tid] = accv;
    __syncthreads();
    if (t == 0) {
        float M0 = red[0][lane];
#pragma unroll
        for (int q = 1; q < 4; q++) M0 = fmaxf(M0, red[0][lane + 64 * q]);
        float L = 0.f, A = 0.f;
#pragma unroll
        for (int q = 0; q < 4; q++) {
            float w = __expf(red[0][lane + 64 * q] - M0);
            L += red[1][lane + 64 * q] * w;
            A += red[2][lane + 64 * q] * w;
        }
        pbase[0] = M0; pbase[Nn] = L; pbase[2 * Nn] = A;
    }
}

// ---------------- K6: merge j-splits, add cvec ----------------
__global__ void merge_kernel(const float* __restrict__ partials,
                             const float* __restrict__ cvec,
                             float* __restrict__ out) {
    int idx = blockIdx.x * blockDim.x + threadIdx.x;   // B*N
    int b = idx >> 12;
    int n = idx & (Nn - 1);
    const float* pb = partials + (size_t)b * JSPLIT * 3 * Nn + n;
    float M0 = -1e30f;
#pragma unroll
    for (int s = 0; s < JSPLIT; s++) M0 = fmaxf(M0, pb[(s * 3) * (size_t)Nn]);
    float L = 0.f, A = 0.f;
#pragma unroll
    for (int s = 0; s < JSPLIT; s++) {
        float w = __expf(pb[(s * 3) * (size_t)Nn] - M0);
        L += pb[(s * 3 + 1) * (size_t)Nn] * w;
        A += pb[(s * 3 + 2) * (size_t)Nn] * w;
    }
    out[idx] = A / L + cvec[n];
}

extern "C" void kernel_launch(void* const* d_in, const int* in_sizes, int n_in,
                              void* d_out, int out_size, void* d_ws, size_t ws_size,
                              hipStream_t stream) {
    (void)in_sizes; (void)n_in; (void)out_size; (void)ws_size;
    const float* input  = (const float*)d_in[0];   // (B,S,I,C)
    const float* E      = (const float*)d_in[1];   // (N,C)
    const float* W      = (const float*)d_in[2];   // (C,C)
    const float* bias   = (const float*)d_in[3];   // (C,)
    const int*   ids    = (const int*)d_in[4];     // (B,S,I)
    const int*   seqlen = (const int*)d_in[5];     // (B,)
    float* out = (float*)d_out;

    // workspace layout — zeroed region first: [cnt | Mcnt | meansC]
    int*   cnt     = (int*)d_ws;                              // B*N
    int*   Mcnt    = cnt + (size_t)Bb * Nn;                   // 16 (8 used)
    float* meansC  = (float*)(Mcnt + 16);                     // B*MAXM*C
    int*   slotmap = (int*)(meansC + (size_t)Bb * MAXM * Cc); // B*N
    float* invc    = (float*)(slotmap + (size_t)Bb * Nn);     // B*N
    float* Fbuf    = invc + (size_t)Bb * Nn;                  // N*C
    float* cvec    = Fbuf + (size_t)Nn * Cc;                  // N
    float* partials= cvec + Nn;                               // B*JSPLIT*3*N

    size_t zero_bytes = ((size_t)Bb * Nn + 16) * sizeof(int)
                      + (size_t)Bb * MAXM * Cc * sizeof(float);
    hipMemsetAsync(d_ws, 0, zero_bytes, stream);

    count_kernel  <<<(NPOS + 255) / 256, 256, 0, stream>>>(ids, seqlen, cnt);
    slot_kernel   <<<Bb * Nn / 256, 256, 0, stream>>>(cnt, Mcnt, slotmap, invc);
    scatter_kernel<<<(NPOS * 64 + 255) / 256, 256, 0, stream>>>(input, ids, seqlen, slotmap, invc, meansC);
    proj_kernel   <<<Nn / 4, 256, 0, stream>>>(E, W, bias, Fbuf, cvec);
    main_kernel   <<<Bb * JSPLIT * 64, 256, 0, stream>>>(E, Fbuf, meansC, Mcnt, partials);
    merge_kernel  <<<Bb * Nn / 256, 256, 0, stream>>>(partials, cvec, out);
}

// Round 3
// 149.810 us; speedup vs baseline: 1.3638x; 1.2572x over previous
//
#include <hip/hip_runtime.h>

#define Bb 8
#define Ss 50
#define Ii 20
#define Cc 64
#define Nn 4096
#define MAXM 1024
#define JSPLIT 4
#define POSB (Ss * Ii)   // 1000 positions per batch

typedef float v16f __attribute__((ext_vector_type(16)));

// ---------------- K1: per-batch linked lists + compact slot assignment ----------------
// 8 blocks (one per batch), 1024 threads. No global atomics, no pre-zeroed memory.
__global__ void build_kernel(const int* __restrict__ ids,
                             const int* __restrict__ seqlen,
                             int* __restrict__ slotHead,
                             int* __restrict__ gnext,
                             int* __restrict__ Mcnt) {
    __shared__ int head[Nn];
    __shared__ int mcnt;
    int b = blockIdx.x;
    int tid = threadIdx.x;
    for (int i = tid; i < Nn; i += 1024) head[i] = -1;
    if (tid == 0) mcnt = 0;
    __syncthreads();
    int P = seqlen[b] * Ii;          // masked positions are exactly p < P
    if (tid < P) {
        int id = ids[b * POSB + tid];
        int old = atomicExch(&head[id], tid);
        gnext[b * POSB + tid] = old;
    }
    __syncthreads();
    for (int i = tid; i < Nn; i += 1024) {
        int h = head[i];
        if (h >= 0) {
            int slot = atomicAdd(&mcnt, 1);
            slotHead[b * MAXM + slot] = h;
        }
    }
    __syncthreads();
    if (tid == 0) Mcnt[b] = mcnt;
}

// ---------------- K2: gather means (one wave per (b,slot)) ----------------
__global__ void mean_kernel(const float* __restrict__ input,
                            const int* __restrict__ slotHead,
                            const int* __restrict__ gnext,
                            const int* __restrict__ Mcnt,
                            float* __restrict__ meansC) {
    int w = (blockIdx.x * blockDim.x + threadIdx.x) >> 6;
    int lane = threadIdx.x & 63;
    int b = w >> 10;                 // MAXM waves per batch
    int slot = w & (MAXM - 1);
    if (slot >= Mcnt[b]) return;     // wave-uniform
    int p = slotHead[b * MAXM + slot];
    float sum = 0.f; int k = 0;
    while (p >= 0) {
        sum += input[((size_t)(b * POSB + p)) * Cc + lane];
        k++;
        p = gnext[b * POSB + p];
    }
    meansC[((size_t)(b * MAXM + slot)) * Cc + lane] = sum / (float)k;
}

// ---------------- K3: F = E @ W ; cvec = E @ bias ----------------
__global__ void proj_kernel(const float* __restrict__ E,
                            const float* __restrict__ W,
                            const float* __restrict__ bias,
                            float* __restrict__ Fbuf,
                            float* __restrict__ cvec) {
    __shared__ float wlds[Cc * Cc];
    __shared__ float elds[4 * Cc];
    int tid = threadIdx.x;
    int n0 = blockIdx.x * 4;
#pragma unroll
    for (int i = 0; i < 16; i++) wlds[tid + 256 * i] = W[tid + 256 * i];
    int nl = tid >> 6, k = tid & 63;
    elds[tid] = E[(size_t)(n0 + nl) * Cc + k];
    __syncthreads();
    float acc = 0.f;
#pragma unroll
    for (int c = 0; c < Cc; c++) acc = fmaf(elds[nl * Cc + c], wlds[c * Cc + k], acc);
    Fbuf[(size_t)(n0 + nl) * Cc + k] = acc;
    float p = elds[nl * Cc + k] * bias[k];
#pragma unroll
    for (int off = 32; off; off >>= 1) p += __shfl_down(p, off);
    if (k == 0) cvec[n0 + nl] = p;
}

// pin 16 floats into VGPRs (loop-carried => compiler must keep resident)
#define PIN16(A, o) asm volatile("" \
    : "+v"(A[o+0]),"+v"(A[o+1]),"+v"(A[o+2]),"+v"(A[o+3]), \
      "+v"(A[o+4]),"+v"(A[o+5]),"+v"(A[o+6]),"+v"(A[o+7]), \
      "+v"(A[o+8]),"+v"(A[o+9]),"+v"(A[o+10]),"+v"(A[o+11]), \
      "+v"(A[o+12]),"+v"(A[o+13]),"+v"(A[o+14]),"+v"(A[o+15]))

// ---------------- K4: fused scores/online-softmax/combine (j-split partials) ----------------
__global__ __launch_bounds__(256, 3) void main_kernel(
    const float* __restrict__ E, const float* __restrict__ Fbuf,
    const float* __restrict__ meansC, const int* __restrict__ Mcnt,
    float* __restrict__ partials) {
    int ntile = blockIdx.x & 63;     // fastest -> co-resident blocks share mean range
    int bs = blockIdx.x >> 6;
    int s = bs & (JSPLIT - 1);
    int b = bs >> 2;
    int tid = threadIdx.x;
    int t = tid >> 6;                // wave id: 4-way j interleave within block
    int lane = tid & 63;
    int n = ntile * 64 + lane;

    int M = Mcnt[b];
    int chunk = (M + JSPLIT - 1) / JSPLIT;
    int j0 = s * chunk;
    int j1 = min(M, j0 + chunk);

    float* pbase = partials + ((size_t)(b * JSPLIT + s) * 3) * Nn + n;
    if (j0 >= j1) {                  // empty split still must write (ws is poisoned)
        if (t == 0) { pbase[0] = -1e30f; pbase[Nn] = 0.f; pbase[2 * Nn] = 0.f; }
        return;
    }

    // E/F rows resident: 128 VGPRs
    float ev[64], fv[64];
    {
        const float4* ep = (const float4*)(E + (size_t)n * Cc);
        const float4* fp = (const float4*)(Fbuf + (size_t)n * Cc);
#pragma unroll
        for (int i = 0; i < 16; i++) {
            float4 a = ep[i], c = fp[i];
            ev[4*i] = a.x; ev[4*i+1] = a.y; ev[4*i+2] = a.z; ev[4*i+3] = a.w;
            fv[4*i] = c.x; fv[4*i+1] = c.y; fv[4*i+2] = c.z; fv[4*i+3] = c.w;
        }
    }

    const float* mbase = meansC + (size_t)b * MAXM * Cc;
    float m0 = -1e30f, l = 0.f, accv = 0.f;

#pragma unroll 1
    for (int j = j0 + t; j < j1; j += JSPLIT) {
        // force E/F residency across the backedge
        PIN16(ev, 0); PIN16(ev, 16); PIN16(ev, 32); PIN16(ev, 48);
        PIN16(fv, 0); PIN16(fv, 16); PIN16(fv, 32); PIN16(fv, 48);

        int ju = __builtin_amdgcn_readfirstlane(j);
        const float* p = mbase + (size_t)ju * Cc;
        v16f ma, mb2, mc, md;                  // means -> SGPRs (no VMEM in loop)
        asm volatile("s_load_dwordx16 %0, %4, 0x0\n\t"
                     "s_load_dwordx16 %1, %4, 0x40\n\t"
                     "s_load_dwordx16 %2, %4, 0x80\n\t"
                     "s_load_dwordx16 %3, %4, 0xc0\n\t"
                     "s_waitcnt lgkmcnt(0)"
                     : "=&s"(ma), "=&s"(mb2), "=&s"(mc), "=&s"(md)
                     : "s"(p));

        float de0 = 0.f, de1 = 0.f, de2 = 0.f, de3 = 0.f;
        float df0 = 0.f, df1 = 0.f, df2 = 0.f, df3 = 0.f;
#pragma unroll
        for (int c = 0; c < 16; c++) {
            de0 = fmaf(ma[c],  ev[c],      de0);  df0 = fmaf(ma[c],  fv[c],      df0);
            de1 = fmaf(mb2[c], ev[16 + c], de1);  df1 = fmaf(mb2[c], fv[16 + c], df1);
            de2 = fmaf(mc[c],  ev[32 + c], de2);  df2 = fmaf(mc[c],  fv[32 + c], df2);
            de3 = fmaf(md[c],  ev[48 + c], de3);  df3 = fmaf(md[c],  fv[48 + c], df3);
        }
        float de = (de0 + de1) + (de2 + de3);
        float df = (df0 + df1) + (df2 + df3);

        float sc = de > 0.f ? de : 0.2f * de;    // leaky_relu 0.2
        float ex = __expf(-fabsf(sc - m0));
        bool sg = sc > m0;
        float pnum = sg ? 1.0f : ex;
        float alpha = sg ? ex : 1.0f;
        m0 = fmaxf(m0, sc);
        l = l * alpha + pnum;
        accv = accv * alpha + pnum * df;
    }

    __shared__ float red[3][256];
    red[0][tid] = m0; red[1][tid] = l; red[2][tid] = accv;
    __syncthreads();
    if (t == 0) {
        float M0 = red[0][lane];
#pragma unroll
        for (int q = 1; q < 4; q++) M0 = fmaxf(M0, red[0][lane + 64 * q]);
        float L = 0.f, A = 0.f;
#pragma unroll
        for (int q = 0; q < 4; q++) {
            float w = __expf(red[0][lane + 64 * q] - M0);
            L += red[1][lane + 64 * q] * w;
            A += red[2][lane + 64 * q] * w;
        }
        pbase[0] = M0; pbase[Nn] = L; pbase[2 * Nn] = A;
    }
}

// ---------------- K5: merge j-splits, add cvec ----------------
__global__ void merge_kernel(const float* __restrict__ partials,
                             const float* __restrict__ cvec,
                             float* __restrict__ out) {
    int idx = blockIdx.x * blockDim.x + threadIdx.x;   // B*N
    int b = idx >> 12;
    int n = idx & (Nn - 1);
    const float* pb = partials + (size_t)b * JSPLIT * 3 * Nn + n;
    float M0 = -1e30f;
#pragma unroll
    for (int s = 0; s < JSPLIT; s++) M0 = fmaxf(M0, pb[(s * 3) * (size_t)Nn]);
    float L = 0.f, A = 0.f;
#pragma unroll
    for (int s = 0; s < JSPLIT; s++) {
        float w = __expf(pb[(s * 3) * (size_t)Nn] - M0);
        L += pb[(s * 3 + 1) * (size_t)Nn] * w;
        A += pb[(s * 3 + 2) * (size_t)Nn] * w;
    }
    out[idx] = A / L + cvec[n];
}

extern "C" void kernel_launch(void* const* d_in, const int* in_sizes, int n_in,
                              void* d_out, int out_size, void* d_ws, size_t ws_size,
                              hipStream_t stream) {
    (void)in_sizes; (void)n_in; (void)out_size; (void)ws_size;
    const float* input  = (const float*)d_in[0];   // (B,S,I,C)
    const float* E      = (const float*)d_in[1];   // (N,C)
    const float* W      = (const float*)d_in[2];   // (C,C)
    const float* bias   = (const float*)d_in[3];   // (C,)
    const int*   ids    = (const int*)d_in[4];     // (B,S,I)
    const int*   seqlen = (const int*)d_in[5];     // (B,)
    float* out = (float*)d_out;

    // workspace (nothing needs pre-zeroing)
    int*   slotHead = (int*)d_ws;                               // B*MAXM
    int*   gnext    = slotHead + (size_t)Bb * MAXM;             // B*POSB
    int*   Mcnt     = gnext + (size_t)Bb * POSB;                // 16 (8 used)
    float* meansC   = (float*)(Mcnt + 16);                      // B*MAXM*C
    float* Fbuf     = meansC + (size_t)Bb * MAXM * Cc;          // N*C
    float* cvec     = Fbuf + (size_t)Nn * Cc;                   // N
    float* partials = cvec + Nn;                                // B*JSPLIT*3*N

    build_kernel<<<Bb, 1024, 0, stream>>>(ids, seqlen, slotHead, gnext, Mcnt);
    mean_kernel <<<Bb * MAXM / 4, 256, 0, stream>>>(input, slotHead, gnext, Mcnt, meansC);
    proj_kernel <<<Nn / 4, 256, 0, stream>>>(E, W, bias, Fbuf, cvec);
    main_kernel <<<Bb * JSPLIT * 64, 256, 0, stream>>>(E, Fbuf, meansC, Mcnt, partials);
    merge_kernel<<<Bb * Nn / 256, 256, 0, stream>>>(partials, cvec, out);
}

// Round 5
// 119.054 us; speedup vs baseline: 1.7161x; 1.2583x over previous
//
#include <hip/hip_runtime.h>

#define Bb 8
#define Ss 50
#define Ii 20
#define Cc 64
#define Nn 4096
#define MAXM 1024
#define POSB (Ss * Ii)    // 1000

typedef unsigned short ushort_t;
typedef __attribute__((ext_vector_type(8))) short short8;   // 8 bf16 = 4 VGPRs (MFMA A/B frag)
typedef __attribute__((ext_vector_type(4))) float f32x4;    // MFMA C/D frag

__device__ inline ushort_t bf16_rn(float x) {
    unsigned u = __float_as_uint(x);
    u = u + 0x7FFFu + ((u >> 16) & 1u);     // round-to-nearest-even
    return (ushort_t)(u >> 16);
}
__device__ inline float bf16_f(ushort_t h) { return __uint_as_float(((unsigned)h) << 16); }

// ---------------- K1: role-split aux ----------------
// blocks 0..7   : per-batch compact lists + means -> bf16 hi/lo
// blocks 8..263 : F = E @ W (16 rows each), E/F bf16 hi/lo, cvec = E @ bias
__global__ __launch_bounds__(1024) void aux_kernel(
    const float* __restrict__ input, const int* __restrict__ ids,
    const int* __restrict__ seqlen, const float* __restrict__ E,
    const float* __restrict__ W, const float* __restrict__ bias,
    int* __restrict__ Mcnt, float* __restrict__ cvec,
    ushort_t* __restrict__ Mhi, ushort_t* __restrict__ Mlo,
    ushort_t* __restrict__ Ehi, ushort_t* __restrict__ Elo,
    ushort_t* __restrict__ Fhi, ushort_t* __restrict__ Flo) {
    __shared__ int smem[6144];            // 24 KB, aliased per role
    int tid = threadIdx.x;

    if (blockIdx.x < Bb) {
        int b = blockIdx.x;
        int* head = smem;                 // 4096
        int* nxt = smem + Nn;             // 1024
        int* slotH = smem + Nn + 1024;    // 1024
        __shared__ int mcnt;
        for (int i = tid; i < Nn; i += 1024) head[i] = -1;
        if (tid == 0) mcnt = 0;
        __syncthreads();
        int P = seqlen[b] * Ii;
        if (tid < P) {
            int id = ids[b * POSB + tid];
            nxt[tid] = atomicExch(&head[id], tid);
        }
        __syncthreads();
        for (int i = tid; i < Nn; i += 1024) {
            int h = head[i];
            if (h >= 0) slotH[atomicAdd(&mcnt, 1)] = h;
        }
        __syncthreads();
        int M = mcnt;
        if (tid == 0) Mcnt[b] = M;
        int lane = tid & 63;
        for (int slot = tid >> 6; slot < M; slot += 16) {
            int p = slotH[slot];
            float sum = 0.f; int k = 0;
            while (p >= 0) {
                sum += input[((size_t)(b * POSB + p)) * Cc + lane];
                k++;
                p = nxt[p];
            }
            float mv = sum / (float)k;
            ushort_t h = bf16_rn(mv);
            size_t o = ((size_t)(b * MAXM + slot)) * Cc + lane;
            Mhi[o] = h;
            Mlo[o] = bf16_rn(mv - bf16_f(h));
        }
    } else {
        int pb = blockIdx.x - Bb;
        float* wlds = (float*)smem;             // 4096 floats
        float* elds = (float*)smem + 4096;      // 1024 floats
        int n0 = pb * 16;
#pragma unroll
        for (int i = 0; i < 4; i++) wlds[tid + 1024 * i] = W[tid + 1024 * i];
        float ev = E[(size_t)n0 * Cc + tid];
        elds[tid] = ev;
        __syncthreads();
        int nl = tid >> 6, k = tid & 63;
        float acc = 0.f;
#pragma unroll
        for (int c = 0; c < Cc; c++) acc = fmaf(elds[nl * Cc + c], wlds[c * Cc + k], acc);
        size_t o = (size_t)(n0 + nl) * Cc + k;
        ushort_t fh = bf16_rn(acc);
        Fhi[o] = fh; Flo[o] = bf16_rn(acc - bf16_f(fh));
        ushort_t eh = bf16_rn(ev);
        Ehi[o] = eh; Elo[o] = bf16_rn(ev - bf16_f(eh));
        float p = ev * bias[k];
#pragma unroll
        for (int off = 32; off; off >>= 1) p += __shfl_down(p, off);
        if (k == 0) cvec[n0 + nl] = p;
    }
}

#define MFMA(A, B, C) __builtin_amdgcn_mfma_f32_16x16x32_bf16(A, B, C, 0, 0, 0)

// ---------------- K2: MFMA scores + online softmax + combine ----------------
// block = (b, 64-n tile); 4 waves x 16 n-cols each; loop m in 16-tiles.
__global__ __launch_bounds__(256) void main_kernel(
    const ushort_t* __restrict__ Ehi, const ushort_t* __restrict__ Elo,
    const ushort_t* __restrict__ Fhi, const ushort_t* __restrict__ Flo,
    const ushort_t* __restrict__ Mhi, const ushort_t* __restrict__ Mlo,
    const int* __restrict__ Mcnt, const float* __restrict__ cvec,
    float* __restrict__ out) {
    int idx = blockIdx.x;
    int ntile = idx >> 3;
    int b = (idx + (idx >> 3) + (idx >> 8)) & 7;   // batch mix across CU round-robin
    int tid = threadIdx.x;
    int wave = tid >> 6, lane = tid & 63;
    int kq = lane >> 4;                            // 0..3 (K-subgroup / C-row group)
    int n = ntile * 64 + wave * 16 + (lane & 15);

    // B-operand frags (loop-invariant): row-major [n][k], lane k-window = kq*8..+8
    size_t nb = (size_t)n * Cc + kq * 8;
    short8 Eh0 = *(const short8*)(Ehi + nb),      Eh1 = *(const short8*)(Ehi + nb + 32);
    short8 El0 = *(const short8*)(Elo + nb),      El1 = *(const short8*)(Elo + nb + 32);
    short8 Fh0 = *(const short8*)(Fhi + nb),      Fh1 = *(const short8*)(Fhi + nb + 32);
    short8 Fl0 = *(const short8*)(Flo + nb),      Fl1 = *(const short8*)(Flo + nb + 32);

    int M = Mcnt[b];
    int nmt = (M + 15) >> 4;
    size_t ab = ((size_t)(b * MAXM) + (lane & 15)) * Cc + kq * 8;

    // prefetch A-frags for m-tile 0
    short8 Ah0 = *(const short8*)(Mhi + ab),      Ah1 = *(const short8*)(Mhi + ab + 32);
    short8 Al0 = *(const short8*)(Mlo + ab),      Al1 = *(const short8*)(Mlo + ab + 32);

    float m0 = -1e30f, l = 0.f, av = 0.f;
    int rowg = kq * 4;

#pragma unroll 1
    for (int mt = 0; mt < nmt; mt++) {
        int mtn = (mt + 1 < nmt) ? mt + 1 : mt;
        size_t an = ab + (size_t)mtn * (16 * Cc);
        short8 Nh0 = *(const short8*)(Mhi + an), Nh1 = *(const short8*)(Mhi + an + 32);
        short8 Nl0 = *(const short8*)(Mlo + an), Nl1 = *(const short8*)(Mlo + an + 32);

        f32x4 S = {0.f, 0.f, 0.f, 0.f}, D = {0.f, 0.f, 0.f, 0.f};
        // scores: (hi+lo)x(hi+lo) minus lo*lo  (error ~2^-18 rel)
        S = MFMA(Ah0, Eh0, S); S = MFMA(Ah1, Eh1, S);
        S = MFMA(Ah0, El0, S); S = MFMA(Ah1, El1, S);
        S = MFMA(Al0, Eh0, S); S = MFMA(Al1, Eh1, S);
        D = MFMA(Ah0, Fh0, D); D = MFMA(Ah1, Fh1, D);
        D = MFMA(Ah0, Fl0, D); D = MFMA(Ah1, Fl1, D);
        D = MFMA(Al0, Fh0, D); D = MFMA(Al1, Fh1, D);

        int mrow = mt * 16 + rowg;
#pragma unroll
        for (int r = 0; r < 4; r++) {
            if (mrow + r < M) {
                float s = S[r];
                float sc = s > 0.f ? s : 0.2f * s;     // leaky_relu 0.2
                float df = D[r];
                float ex = __expf(-fabsf(sc - m0));
                bool sg = sc > m0;
                float p = sg ? 1.f : ex;
                float al = sg ? ex : 1.f;
                m0 = fmaxf(m0, sc);
                l = l * al + p;
                av = av * al + p * df;
            }
        }
        Ah0 = Nh0; Ah1 = Nh1; Al0 = Nl0; Al1 = Nl1;
    }

    // merge the 4 row-groups sharing column n (lanes xor 16, 32)
#pragma unroll
    for (int mask = 16; mask <= 32; mask <<= 1) {
        float m0b = __shfl_xor(m0, mask);
        float lb  = __shfl_xor(l,  mask);
        float avb = __shfl_xor(av, mask);
        float M0 = fmaxf(m0, m0b);
        float w1 = __expf(m0 - M0), w2 = __expf(m0b - M0);
        m0 = M0;
        l  = l * w1 + lb * w2;
        av = av * w1 + avb * w2;
    }
    if (kq == 0) out[b * Nn + n] = av / l + cvec[n];
}

extern "C" void kernel_launch(void* const* d_in, const int* in_sizes, int n_in,
                              void* d_out, int out_size, void* d_ws, size_t ws_size,
                              hipStream_t stream) {
    (void)in_sizes; (void)n_in; (void)out_size; (void)ws_size;
    const float* input  = (const float*)d_in[0];
    const float* E      = (const float*)d_in[1];
    const float* W      = (const float*)d_in[2];
    const float* bias   = (const float*)d_in[3];
    const int*   ids    = (const int*)d_in[4];
    const int*   seqlen = (const int*)d_in[5];
    float* out = (float*)d_out;

    int*      Mcnt = (int*)d_ws;                          // 16
    float*    cvec = (float*)(Mcnt + 16);                 // N
    ushort_t* Mhi  = (ushort_t*)(cvec + Nn);              // B*MAXM*C
    ushort_t* Mlo  = Mhi + (size_t)Bb * MAXM * Cc;
    ushort_t* Ehi  = Mlo + (size_t)Bb * MAXM * Cc;        // N*C
    ushort_t* Elo  = Ehi + (size_t)Nn * Cc;
    ushort_t* Fhi  = Elo + (size_t)Nn * Cc;
    ushort_t* Flo  = Fhi + (size_t)Nn * Cc;

    aux_kernel <<<Bb + Nn / 16, 1024, 0, stream>>>(input, ids, seqlen, E, W, bias,
                                                   Mcnt, cvec, Mhi, Mlo, Ehi, Elo, Fhi, Flo);
    main_kernel<<<Bb * (Nn / 64), 256, 0, stream>>>(Ehi, Elo, Fhi, Flo, Mhi, Mlo,
                                                    Mcnt, cvec, out);
}

// Round 6
// 104.212 us; speedup vs baseline: 1.9605x; 1.1424x over previous
//
#include <hip/hip_runtime.h>

#define Bb 8
#define Ss 50
#define Ii 20
#define Cc 64
#define Nn 4096
#define MAXM 1024
#define POSB (Ss * Ii)    // 1000

typedef unsigned short ushort_t;
typedef __attribute__((ext_vector_type(8))) short short8;   // 8 bf16 = 4 VGPRs (MFMA A/B frag)
typedef __attribute__((ext_vector_type(4))) float f32x4;    // MFMA C/D frag

__device__ inline ushort_t bf16_rn(float x) {
    unsigned u = __float_as_uint(x);
    u = u + 0x7FFFu + ((u >> 16) & 1u);     // round-to-nearest-even
    return (ushort_t)(u >> 16);
}
__device__ inline float bf16_f(ushort_t h) { return __uint_as_float(((unsigned)h) << 16); }

// ---------------- K1: role-split aux ----------------
// blocks 0..7   : per-batch linked-list build + compact slot assignment (LDS atomics only)
// blocks 8..263 : F = E @ W (16 rows each), E/F bf16 hi/lo, cvec = E @ bias
__global__ __launch_bounds__(1024) void aux_kernel(
    const float* __restrict__ input, const int* __restrict__ ids,
    const int* __restrict__ seqlen, const float* __restrict__ E,
    const float* __restrict__ W, const float* __restrict__ bias,
    int* __restrict__ Mcnt, int* __restrict__ slotHead, int* __restrict__ gnext,
    float* __restrict__ cvec,
    ushort_t* __restrict__ Ehi, ushort_t* __restrict__ Elo,
    ushort_t* __restrict__ Fhi, ushort_t* __restrict__ Flo) {
    __shared__ int smem[5120];            // 20 KB, aliased per role
    int tid = threadIdx.x;

    if (blockIdx.x < Bb) {
        // ---- build: lists + compact slots for batch b ----
        int b = blockIdx.x;
        int* head = smem;                 // 4096
        __shared__ int mcnt;
        for (int i = tid; i < Nn; i += 1024) head[i] = -1;
        if (tid == 0) mcnt = 0;
        __syncthreads();
        int P = seqlen[b] * Ii;           // masked positions are exactly p < P
        if (tid < P) {
            int id = ids[b * POSB + tid];
            gnext[b * POSB + tid] = atomicExch(&head[id], tid);
        }
        __syncthreads();
        for (int i = tid; i < Nn; i += 1024) {
            int h = head[i];
            if (h >= 0) slotHead[b * MAXM + atomicAdd(&mcnt, 1)] = h;
        }
        __syncthreads();
        if (tid == 0) Mcnt[b] = mcnt;
    } else {
        // ---- proj: 16 rows of F per block + hi/lo splits + cvec ----
        int pb = blockIdx.x - Bb;
        float* wlds = (float*)smem;             // 4096 floats
        float* elds = (float*)smem + 4096;      // 1024 floats
        int n0 = pb * 16;
#pragma unroll
        for (int i = 0; i < 4; i++) wlds[tid + 1024 * i] = W[tid + 1024 * i];
        float ev = E[(size_t)n0 * Cc + tid];
        elds[tid] = ev;
        __syncthreads();
        int nl = tid >> 6, k = tid & 63;
        float acc = 0.f;
#pragma unroll
        for (int c = 0; c < Cc; c++) acc = fmaf(elds[nl * Cc + c], wlds[c * Cc + k], acc);
        size_t o = (size_t)(n0 + nl) * Cc + k;
        ushort_t fh = bf16_rn(acc);
        Fhi[o] = fh; Flo[o] = bf16_rn(acc - bf16_f(fh));
        ushort_t eh = bf16_rn(ev);
        Ehi[o] = eh; Elo[o] = bf16_rn(ev - bf16_f(eh));
        float p = ev * bias[k];
#pragma unroll
        for (int off = 32; off; off >>= 1) p += __shfl_down(p, off);
        if (k == 0) cvec[n0 + nl] = p;
    }
}

// ---------------- K2: mean gather — ONE WAVE PER SLOT (8192 waves) ----------------
__global__ __launch_bounds__(256) void mean_kernel(
    const float* __restrict__ input, const int* __restrict__ slotHead,
    const int* __restrict__ gnext, const int* __restrict__ Mcnt,
    ushort_t* __restrict__ Mhi, ushort_t* __restrict__ Mlo) {
    int w = (blockIdx.x * 256 + threadIdx.x) >> 6;
    int lane = threadIdx.x & 63;
    int b = w >> 10;
    int slot = w & (MAXM - 1);
    if (slot >= Mcnt[b]) return;          // wave-uniform
    int p = slotHead[b * MAXM + slot];
    float sum = 0.f; int k = 0;
    while (p >= 0) {
        sum += input[((size_t)(b * POSB + p)) * Cc + lane];
        k++;
        p = gnext[b * POSB + p];
    }
    float mv = sum / (float)k;
    ushort_t h = bf16_rn(mv);
    size_t o = ((size_t)(b * MAXM + slot)) * Cc + lane;
    Mhi[o] = h;
    Mlo[o] = bf16_rn(mv - bf16_f(h));
}

#define MFMA(A, B, C) __builtin_amdgcn_mfma_f32_16x16x32_bf16(A, B, C, 0, 0, 0)

// ---------------- K3: MFMA scores + online softmax + combine ----------------
// block = (b, 64-n tile); 4 waves x 16 n-cols each; loop m in 16-tiles.
__global__ __launch_bounds__(256) void main_kernel(
    const ushort_t* __restrict__ Ehi, const ushort_t* __restrict__ Elo,
    const ushort_t* __restrict__ Fhi, const ushort_t* __restrict__ Flo,
    const ushort_t* __restrict__ Mhi, const ushort_t* __restrict__ Mlo,
    const int* __restrict__ Mcnt, const float* __restrict__ cvec,
    float* __restrict__ out) {
    int idx = blockIdx.x;
    int ntile = idx >> 3;
    int b = (idx + (idx >> 3) + (idx >> 8)) & 7;   // batch mix across CU round-robin
    int tid = threadIdx.x;
    int wave = tid >> 6, lane = tid & 63;
    int kq = lane >> 4;                            // 0..3 (K-subgroup / C-row group)
    int n = ntile * 64 + wave * 16 + (lane & 15);

    // B-operand frags (loop-invariant): row-major [n][k], lane k-window = kq*8..+8
    size_t nb = (size_t)n * Cc + kq * 8;
    short8 Eh0 = *(const short8*)(Ehi + nb),      Eh1 = *(const short8*)(Ehi + nb + 32);
    short8 El0 = *(const short8*)(Elo + nb),      El1 = *(const short8*)(Elo + nb + 32);
    short8 Fh0 = *(const short8*)(Fhi + nb),      Fh1 = *(const short8*)(Fhi + nb + 32);
    short8 Fl0 = *(const short8*)(Flo + nb),      Fl1 = *(const short8*)(Flo + nb + 32);

    int M = Mcnt[b];
    int nmt = (M + 15) >> 4;
    size_t ab = ((size_t)(b * MAXM) + (lane & 15)) * Cc + kq * 8;

    // prefetch A-frags for m-tile 0
    short8 Ah0 = *(const short8*)(Mhi + ab),      Ah1 = *(const short8*)(Mhi + ab + 32);
    short8 Al0 = *(const short8*)(Mlo + ab),      Al1 = *(const short8*)(Mlo + ab + 32);

    float m0 = -1e30f, l = 0.f, av = 0.f;
    int rowg = kq * 4;

#pragma unroll 1
    for (int mt = 0; mt < nmt; mt++) {
        int mtn = (mt + 1 < nmt) ? mt + 1 : mt;
        size_t an = ab + (size_t)mtn * (16 * Cc);
        short8 Nh0 = *(const short8*)(Mhi + an), Nh1 = *(const short8*)(Mhi + an + 32);
        short8 Nl0 = *(const short8*)(Mlo + an), Nl1 = *(const short8*)(Mlo + an + 32);

        f32x4 S = {0.f, 0.f, 0.f, 0.f}, D = {0.f, 0.f, 0.f, 0.f};
        // split-bf16: hi*hi + hi*lo + lo*hi (error ~2^-18 rel)
        S = MFMA(Ah0, Eh0, S); S = MFMA(Ah1, Eh1, S);
        S = MFMA(Ah0, El0, S); S = MFMA(Ah1, El1, S);
        S = MFMA(Al0, Eh0, S); S = MFMA(Al1, Eh1, S);
        D = MFMA(Ah0, Fh0, D); D = MFMA(Ah1, Fh1, D);
        D = MFMA(Ah0, Fl0, D); D = MFMA(Ah1, Fl1, D);
        D = MFMA(Al0, Fh0, D); D = MFMA(Al1, Fh1, D);

        int mrow = mt * 16 + rowg;
#pragma unroll
        for (int r = 0; r < 4; r++) {
            if (mrow + r < M) {
                float s = S[r];
                float sc = s > 0.f ? s : 0.2f * s;     // leaky_relu 0.2
                float df = D[r];
                float ex = __expf(-fabsf(sc - m0));
                bool sg = sc > m0;
                float p = sg ? 1.f : ex;
                float al = sg ? ex : 1.f;
                m0 = fmaxf(m0, sc);
                l = l * al + p;
                av = av * al + p * df;
            }
        }
        Ah0 = Nh0; Ah1 = Nh1; Al0 = Nl0; Al1 = Nl1;
    }

    // merge the 4 row-groups sharing column n (lanes xor 16, 32)
#pragma unroll
    for (int mask = 16; mask <= 32; mask <<= 1) {
        float m0b = __shfl_xor(m0, mask);
        float lb  = __shfl_xor(l,  mask);
        float avb = __shfl_xor(av, mask);
        float M0 = fmaxf(m0, m0b);
        float w1 = __expf(m0 - M0), w2 = __expf(m0b - M0);
        m0 = M0;
        l  = l * w1 + lb * w2;
        av = av * w1 + avb * w2;
    }
    if (kq == 0) out[b * Nn + n] = av / l + cvec[n];
}

extern "C" void kernel_launch(void* const* d_in, const int* in_sizes, int n_in,
                              void* d_out, int out_size, void* d_ws, size_t ws_size,
                              hipStream_t stream) {
    (void)in_sizes; (void)n_in; (void)out_size; (void)ws_size;
    const float* input  = (const float*)d_in[0];
    const float* E      = (const float*)d_in[1];
    const float* W      = (const float*)d_in[2];
    const float* bias   = (const float*)d_in[3];
    const int*   ids    = (const int*)d_in[4];
    const int*   seqlen = (const int*)d_in[5];
    float* out = (float*)d_out;

    int*      Mcnt     = (int*)d_ws;                        // 16
    int*      slotHead = Mcnt + 16;                         // B*MAXM
    int*      gnext    = slotHead + Bb * MAXM;              // B*POSB
    float*    cvec     = (float*)(gnext + Bb * POSB);       // N
    ushort_t* Mhi      = (ushort_t*)(cvec + Nn);            // B*MAXM*C
    ushort_t* Mlo      = Mhi + (size_t)Bb * MAXM * Cc;
    ushort_t* Ehi      = Mlo + (size_t)Bb * MAXM * Cc;      // N*C
    ushort_t* Elo      = Ehi + (size_t)Nn * Cc;
    ushort_t* Fhi      = Elo + (size_t)Nn * Cc;
    ushort_t* Flo      = Fhi + (size_t)Nn * Cc;

    aux_kernel <<<Bb + Nn / 16, 1024, 0, stream>>>(input, ids, seqlen, E, W, bias,
                                                   Mcnt, slotHead, gnext, cvec,
                                                   Ehi, Elo, Fhi, Flo);
    mean_kernel<<<Bb * MAXM / 4, 256, 0, stream>>>(input, slotHead, gnext, Mcnt, Mhi, Mlo);
    main_kernel<<<Bb * (Nn / 64), 256, 0, stream>>>(Ehi, Elo, Fhi, Flo, Mhi, Mlo,
                                                    Mcnt, cvec, out);
}